// Round 1
// baseline (791.381 us; speedup 1.0000x reference)
//
#include <hip/hip_runtime.h>

typedef _Float16 half_t;
typedef _Float16 half8  __attribute__((ext_vector_type(8)));
typedef _Float16 half4_t __attribute__((ext_vector_type(4)));
typedef float    floatx4 __attribute__((ext_vector_type(4)));

#define KNN 40

// ---------------------------------------------------------------------------
// Precompute: WkvT (f16, [L][256 n][384 k] = Wk|Wv transposed), qbias[L][128],
// Wofc1[L][128][128] = Wo @ fc1_top.
// ---------------------------------------------------------------------------
__global__ __launch_bounds__(256) void precompute_kernel(
    const float* __restrict__ Wq, const float* __restrict__ Wk,
    const float* __restrict__ Wv, const float* __restrict__ Wo,
    const float* __restrict__ fc1, const float* __restrict__ time_b,
    half_t* __restrict__ WkvT, float* __restrict__ qbias,
    float* __restrict__ Wofc1)
{
  int blk = blockIdx.x, tid = threadIdx.x;
  if (blk < 768) {
    int t = blk * 256 + tid;            // [0, 2*256*384)
    int l = t / 98304;
    int r = t - l * 98304;              // n*384 + k
    int n = r / 384;
    int k = r - n * 384;
    float v = (n < 128) ? Wk[l * 49152 + k * 128 + n]
                        : Wv[l * 49152 + k * 128 + (n - 128)];
    WkvT[t] = (half_t)v;
  } else if (blk == 768) {
    int l = tid >> 7, j = tid & 127;
    float s = 0.f;
    for (int d = 0; d < 128; ++d)
      s += cosf(time_b[d]) * Wq[l * 32768 + (128 + d) * 128 + j];
    qbias[l * 128 + j] = s;
  } else {
    int t = (blk - 769) * 256 + tid;    // [0, 2*128*128)
    int l = t >> 14;
    int r = t & 16383;
    int dd = r >> 7, j = r & 127;
    float s = 0.f;
    for (int m = 0; m < 128; ++m)
      s += Wo[l * 16384 + dd * 128 + m] * fc1[l * 32768 + m * 128 + j];
    Wofc1[t] = s;
  }
}

// ---------------------------------------------------------------------------
// Fused hop aggregation. One block = 3 batches (120 kv rows, padded to 128).
// Phases: src/q staging -> K-loop MFMA GEMM (kk|vv) -> kvT to LDS ->
// scores -> softmax -> attn@V -> (Wofc1 + fc1_bot) relu -> fc2 -> out.
// ---------------------------------------------------------------------------
__global__ __launch_bounds__(256, 2) void hop_kernel(
    const float* __restrict__ nf,        // node_features [100000][128]
    const float* __restrict__ ne_src,    // layer0: nf (gather); layer1: emb1 (direct)
    int ne_direct,
    const float* __restrict__ ef,        // edge_features [500000][128]
    const int*   __restrict__ src_idx,   // [b_total] source node ids
    const float* __restrict__ tsv, int ts_div,
    const int*   __restrict__ neigh,     // [b_total][40]
    const int*   __restrict__ eidx,      // [b_total][40]
    const float* __restrict__ etimes,    // [b_total][40]
    const float* __restrict__ tw,        // [128]
    const float* __restrict__ tb,        // [128]
    const float* __restrict__ Wq_l,      // [256][128] (top 128 rows used)
    const float* __restrict__ qbias_l,   // [128]
    const half_t* __restrict__ WkvT_l,   // [256][384] f16
    const float* __restrict__ Wofc1_l,   // [128][128]
    const float* __restrict__ fc1b_l,    // [128][128] (fc1 rows 128..255)
    const float* __restrict__ fc2_l,     // [128][128]
    float* __restrict__ out)             // [b_total][128]
{
  // LDS layout (bytes), total 65472 <= 64KB:
  //  phase GEMM : A [128][72] f16 @0 (18432) | BT [256][72] f16 @18432 (36864)
  //  phase attn : kvT [256 col][120 row] f16 @0 (61440)
  //  persistent : q f32 [3][128] @61440 | src f32 [3][128] @62976 |
  //               scores f32 [3][2][40] @64512
  //  reuse      : attnOut/h1 f32 [3][128] @61440 (q dead by then)
  __shared__ __align__(16) char smem[65472];
  half_t* As  = (half_t*)(smem);
  half_t* BTs = (half_t*)(smem + 18432);
  half_t* kvT = (half_t*)(smem);
  float*  qs   = (float*)(smem + 61440);
  float*  srcs = (float*)(smem + 62976);
  float*  scs  = (float*)(smem + 64512);
  float*  attO = (float*)(smem + 61440);
  float*  h1s  = (float*)(smem + 61440);

  const int tid = threadIdx.x;
  const int bbase = blockIdx.x * 3;

  // ---- stage src rows (3 x 128 f32) ----
  for (int i = tid; i < 384; i += 256) {
    int g = i >> 7, dd = i & 127;
    int sn = src_idx[bbase + g];
    srcs[i] = nf[(size_t)sn * 128 + dd];
  }
  __syncthreads();

  // ---- q = src @ Wq_top + qbias (coalesced over j) ----
  {
    int g = tid >> 7, jj = tid & 127;
    const float* sg = srcs + g * 128;
    float s = qbias_l[jj];
    for (int d = 0; d < 128; ++d) s += sg[d] * Wq_l[d * 128 + jj];
    qs[tid] = s;
    if (tid < 128) {                    // third row
      const float* sg2 = srcs + 2 * 128;
      float s2 = qbias_l[jj];
      for (int d = 0; d < 128; ++d) s2 += sg2[d] * Wq_l[d * 128 + jj];
      qs[256 + tid] = s2;
    }
  }
  // visibility of qs ensured by K-loop barriers before first read.

  // ---- per-thread row info for A staging (2 threads per row) ----
  const int r = tid >> 1, hf = tid & 1;
  float dval = 0.f;
  const float* gbase_ne = nullptr;
  const float* gbase_ef = nullptr;
  if (r < 120) {
    int g = r / 40;
    int n = r - g * 40;
    int bg = bbase + g;
    int rowidx = bg * KNN + n;
    int nd = neigh[rowidx];
    int ed = eidx[rowidx];
    dval = tsv[bg / ts_div] - etimes[rowidx];
    gbase_ne = ne_direct ? (ne_src + (size_t)rowidx * 128)
                         : (ne_src + (size_t)nd * 128);
    gbase_ef = ef + (size_t)ed * 128;
  }

  // ---- MFMA accumulators: wave tile 64(M) x 128(N), 4x8 16x16 tiles ----
  floatx4 acc[4][8];
  #pragma unroll
  for (int mi = 0; mi < 4; ++mi)
    #pragma unroll
    for (int ni = 0; ni < 8; ++ni)
      acc[mi][ni] = (floatx4){0.f, 0.f, 0.f, 0.f};

  const int lane = tid & 63;
  const int wv   = tid >> 6;
  const int wm   = (wv & 1) * 64;
  const int wn   = (wv >> 1) * 128;
  const int l15  = lane & 15;
  const int q4   = lane >> 4;

  // ---- K-loop: 6 chunks of 64 (seg 0=NF, 1=time, 2=EF) ----
  for (int kc = 0; kc < 6; ++kc) {
    const int seg  = kc >> 1;
    const int soff = (kc & 1) * 64;

    half_t* Arow = As + r * 72 + hf * 32;
    if (r < 120) {
      if (seg == 1) {
        #pragma unroll
        for (int i2 = 0; i2 < 4; ++i2) {
          half8 h;
          #pragma unroll
          for (int u = 0; u < 8; ++u) {
            int c = soff + hf * 32 + i2 * 8 + u;
            h[u] = (half_t)__cosf(__builtin_fmaf(dval, tw[c], tb[c]));
          }
          *(half8*)(Arow + i2 * 8) = h;
        }
      } else {
        const float* gb = (seg == 0 ? gbase_ne : gbase_ef) + soff + hf * 32;
        #pragma unroll
        for (int i2 = 0; i2 < 4; ++i2) {
          float4 v0 = ((const float4*)gb)[2 * i2];
          float4 v1 = ((const float4*)gb)[2 * i2 + 1];
          half8 h;
          h[0] = (half_t)v0.x; h[1] = (half_t)v0.y;
          h[2] = (half_t)v0.z; h[3] = (half_t)v0.w;
          h[4] = (half_t)v1.x; h[5] = (half_t)v1.y;
          h[6] = (half_t)v1.z; h[7] = (half_t)v1.w;
          *(half8*)(Arow + i2 * 8) = h;
        }
      }
    } else {
      half8 z = {};
      #pragma unroll
      for (int i2 = 0; i2 < 4; ++i2) *(half8*)(Arow + i2 * 8) = z;
    }

    // stage BT: 256 rows x 64 k f16, 4 threads/row
    {
      int p = tid & 3;
      #pragma unroll
      for (int j2 = 0; j2 < 4; ++j2) {
        int n2 = (tid >> 2) + j2 * 64;
        const uint4* gsrc = (const uint4*)(WkvT_l + (size_t)n2 * 384 + kc * 64 + p * 16);
        uint4 w0 = gsrc[0], w1 = gsrc[1];
        uint4* dst = (uint4*)(BTs + n2 * 72 + p * 16);
        dst[0] = w0; dst[1] = w1;
      }
    }
    __syncthreads();

    #pragma unroll
    for (int ks = 0; ks < 2; ++ks) {
      half8 a[4];
      #pragma unroll
      for (int mi = 0; mi < 4; ++mi)
        a[mi] = *(half8*)(As + (wm + mi * 16 + l15) * 72 + ks * 32 + q4 * 8);
      #pragma unroll
      for (int ni = 0; ni < 8; ++ni) {
        half8 b = *(half8*)(BTs + (wn + ni * 16 + l15) * 72 + ks * 32 + q4 * 8);
        #pragma unroll
        for (int mi = 0; mi < 4; ++mi)
          acc[mi][ni] = __builtin_amdgcn_mfma_f32_16x16x32_f16(a[mi], b, acc[mi][ni], 0, 0, 0);
      }
    }
    __syncthreads();
  }

  // ---- write kk|vv to kvT [col][row] f16 (rows < 120) ----
  #pragma unroll
  for (int mi = 0; mi < 4; ++mi) {
    int m0 = wm + mi * 16 + q4 * 4;     // C/D row = quad*4 + reg
    if (m0 < 120) {
      #pragma unroll
      for (int ni = 0; ni < 8; ++ni) {
        int col = wn + ni * 16 + l15;
        half4_t h;
        h[0] = (half_t)acc[mi][ni][0];
        h[1] = (half_t)acc[mi][ni][1];
        h[2] = (half_t)acc[mi][ni][2];
        h[3] = (half_t)acc[mi][ni][3];
        *(half4_t*)(kvT + col * 120 + m0) = h;
      }
    }
  }
  __syncthreads();

  // ---- scores: thread per (g,h,n), 240 threads ----
  if (tid < 240) {
    int g = tid / 80;
    int rem = tid - g * 80;
    int h = rem / 40;
    int n = rem - h * 40;
    int bg = bbase + g;
    bool masked = (neigh[bg * KNN + n] == 0);
    const float* qrow = qs + g * 128 + h * 64;
    int row = g * 40 + n;
    float s = 0.f;
    for (int d = 0; d < 64; ++d)
      s += qrow[d] * (float)kvT[(h * 64 + d) * 120 + row];
    scs[tid] = masked ? -1e9f : s * 0.125f;
  }
  __syncthreads();

  // ---- softmax per (g,h): 6 threads ----
  if (tid < 6) {
    float* sc = scs + tid * 40;
    float mx = -1e30f;
    for (int n = 0; n < 40; ++n) mx = fmaxf(mx, sc[n]);
    float sum = 0.f;
    for (int n = 0; n < 40; ++n) sum += __expf(sc[n] - mx);
    float inv = 1.f / sum;
    for (int n = 0; n < 40; ++n) sc[n] = __expf(sc[n] - mx) * inv;
  }
  __syncthreads();

  // ---- attnOut[g][d] = sum_n attn * vv ----
  {
    float av0, av1 = 0.f;
    {
      int g = tid >> 7, dcol = tid & 127, h = dcol >> 6;
      const float* attn = scs + g * 80 + h * 40;
      const half_t* vcol = kvT + (128 + dcol) * 120 + g * 40;
      float s = 0.f;
      for (int n = 0; n < 40; ++n) s += attn[n] * (float)vcol[n];
      av0 = s;
    }
    if (tid < 128) {
      int dcol = tid, h = dcol >> 6;
      const float* attn = scs + 2 * 80 + h * 40;
      const half_t* vcol = kvT + (128 + dcol) * 120 + 2 * 40;
      float s = 0.f;
      for (int n = 0; n < 40; ++n) s += attn[n] * (float)vcol[n];
      av1 = s;
    }
    attO[tid] = av0;                    // overwrites q region (dead)
    if (tid < 128) attO[256 + tid] = av1;
  }
  __syncthreads();

  // ---- h1 = relu(attnOut @ Wofc1 + src @ fc1_bot) ----
  float hv0, hv1 = 0.f;
  {
    int g = tid >> 7, jj = tid & 127;
    const float* ag = attO + g * 128;
    const float* sg = srcs + g * 128;
    float s = 0.f;
    for (int d = 0; d < 128; ++d)
      s += ag[d] * Wofc1_l[d * 128 + jj] + sg[d] * fc1b_l[d * 128 + jj];
    hv0 = fmaxf(s, 0.f);
  }
  if (tid < 128) {
    int jj = tid;
    const float* ag = attO + 2 * 128;
    const float* sg = srcs + 2 * 128;
    float s = 0.f;
    for (int d = 0; d < 128; ++d)
      s += ag[d] * Wofc1_l[d * 128 + jj] + sg[d] * fc1b_l[d * 128 + jj];
    hv1 = fmaxf(s, 0.f);
  }
  __syncthreads();                      // all attO reads done
  h1s[tid] = hv0;                       // overwrites attO
  if (tid < 128) h1s[256 + tid] = hv1;
  __syncthreads();

  // ---- emb = h1 @ fc2 -> out ----
  {
    int g = tid >> 7, ii = tid & 127;
    const float* hg = h1s + g * 128;
    float s = 0.f;
    for (int j = 0; j < 128; ++j) s += hg[j] * fc2_l[j * 128 + ii];
    out[(size_t)(bbase + g) * 128 + ii] = s;
  }
  if (tid < 128) {
    int ii = tid;
    const float* hg = h1s + 2 * 128;
    float s = 0.f;
    for (int j = 0; j < 128; ++j) s += hg[j] * fc2_l[j * 128 + ii];
    out[(size_t)(bbase + 2) * 128 + ii] = s;
  }
}

// ---------------------------------------------------------------------------
extern "C" void kernel_launch(void* const* d_in, const int* in_sizes, int n_in,
                              void* d_out, int out_size, void* d_ws, size_t ws_size,
                              hipStream_t stream) {
  const float* nf      = (const float*)d_in[0];
  const float* ef      = (const float*)d_in[1];
  const float* tw      = (const float*)d_in[2];
  const float* tb      = (const float*)d_in[3];
  const float* Wq      = (const float*)d_in[4];
  const float* Wk      = (const float*)d_in[5];
  const float* Wv      = (const float*)d_in[6];
  const float* Wo      = (const float*)d_in[7];
  const float* fc1     = (const float*)d_in[8];
  const float* fc2     = (const float*)d_in[9];
  const int*   srcn    = (const int*)d_in[10];
  const float* ts      = (const float*)d_in[11];
  const int*   neigh2  = (const int*)d_in[12];
  const int*   eidx2   = (const int*)d_in[13];
  const float* etimes2 = (const float*)d_in[14];
  const int*   neigh1  = (const int*)d_in[15];
  const int*   eidx1   = (const int*)d_in[16];
  const float* etimes1 = (const float*)d_in[17];

  // workspace layout (16B aligned)
  half_t* WkvT  = (half_t*)d_ws;                          // 393216 B
  float*  qbias = (float*)((char*)d_ws + 393216);         // 1024 B
  float*  Wofc1 = (float*)((char*)d_ws + 394240);         // 131072 B
  float*  emb1  = (float*)((char*)d_ws + 525312);         // 6144000 B

  precompute_kernel<<<dim3(897), dim3(256), 0, stream>>>(
      Wq, Wk, Wv, Wo, fc1, tb, WkvT, qbias, Wofc1);

  // layer 0: 12000 batches, 3 per block
  hop_kernel<<<dim3(4000), dim3(256), 0, stream>>>(
      nf, nf, 0, ef, neigh2, ts, 40, neigh1, eidx1, etimes1, tw, tb,
      Wq, qbias, WkvT, Wofc1, fc1 + 16384, fc2, emb1);

  // layer 1: 300 batches, 3 per block
  hop_kernel<<<dim3(100), dim3(256), 0, stream>>>(
      nf, emb1, 1, ef, srcn, ts, 1, neigh2, eidx2, etimes2, tw, tb,
      Wq + 32768, qbias + 128, WkvT + 98304, Wofc1 + 16384,
      fc1 + 32768 + 16384, fc2 + 16384, (float*)d_out);
}

// Round 2
// 788.876 us; speedup vs baseline: 1.0032x; 1.0032x over previous
//
#include <hip/hip_runtime.h>

typedef _Float16 half_t;
typedef _Float16 half8  __attribute__((ext_vector_type(8)));
typedef _Float16 half4_t __attribute__((ext_vector_type(4)));
typedef float    floatx4 __attribute__((ext_vector_type(4)));

#define KNN 40
#define KVPAD 124   // 62 dwords stride -> 2-way (free) bank pattern

// ---------------------------------------------------------------------------
// Precompute: WkvT (f16, [L][256 n][384 k] = Wk|Wv transposed), qbias[L][128],
// Wofc1[L][128][128] = Wo @ fc1_top.
// ---------------------------------------------------------------------------
__global__ __launch_bounds__(256) void precompute_kernel(
    const float* __restrict__ Wq, const float* __restrict__ Wk,
    const float* __restrict__ Wv, const float* __restrict__ Wo,
    const float* __restrict__ fc1, const float* __restrict__ time_b,
    half_t* __restrict__ WkvT, float* __restrict__ qbias,
    float* __restrict__ Wofc1)
{
  int blk = blockIdx.x, tid = threadIdx.x;
  if (blk < 768) {
    int t = blk * 256 + tid;            // [0, 2*256*384)
    int l = t / 98304;
    int r = t - l * 98304;              // n*384 + k
    int n = r / 384;
    int k = r - n * 384;
    float v = (n < 128) ? Wk[l * 49152 + k * 128 + n]
                        : Wv[l * 49152 + k * 128 + (n - 128)];
    WkvT[t] = (half_t)v;
  } else if (blk == 768) {
    int l = tid >> 7, j = tid & 127;
    float s = 0.f;
    for (int d = 0; d < 128; ++d)
      s += cosf(time_b[d]) * Wq[l * 32768 + (128 + d) * 128 + j];
    qbias[l * 128 + j] = s;
  } else {
    int t = (blk - 769) * 256 + tid;    // [0, 2*128*128)
    int l = t >> 14;
    int r = t & 16383;
    int dd = r >> 7, j = r & 127;
    float s = 0.f;
    for (int m = 0; m < 128; ++m)
      s += Wo[l * 16384 + dd * 128 + m] * fc1[l * 32768 + m * 128 + j];
    Wofc1[t] = s;
  }
}

// ---------------------------------------------------------------------------
// Fused hop aggregation. One block = 3 batches (120 kv rows, padded to 128).
// 512 threads = 8 waves, wave tile 64(M)x64(N) -> acc = 64 VGPR/wave.
// LDS: fragment-ordered A/B tiles (conflict-free ds_read_b128), kvT split
// into kk-pass then vv-pass reusing the B region.
// ---------------------------------------------------------------------------
__global__ __launch_bounds__(512, 4) void hop_kernel(
    const float* __restrict__ nf,        // node_features [100000][128]
    const float* __restrict__ ne_src,    // layer0: nf (gather); layer1: emb1 (direct)
    int ne_direct,
    const float* __restrict__ ef,        // edge_features [500000][128]
    const int*   __restrict__ src_idx,   // [b_total] source node ids
    const float* __restrict__ tsv, int ts_div,
    const int*   __restrict__ neigh,     // [b_total][40]
    const int*   __restrict__ eidx,      // [b_total][40]
    const float* __restrict__ etimes,    // [b_total][40]
    const float* __restrict__ tw,        // [128]
    const float* __restrict__ tb,        // [128]
    const float* __restrict__ Wq_l,      // [256][128] (top 128 rows used)
    const float* __restrict__ qbias_l,   // [128]
    const half_t* __restrict__ WkvT_l,   // [256][384] f16
    const float* __restrict__ Wofc1_l,   // [128][128]
    const float* __restrict__ fc1b_l,    // [128][128] (fc1 rows 128..255)
    const float* __restrict__ fc2_l,     // [128][128]
    float* __restrict__ out)             // [b_total][128]
{
  // LDS layout (bytes), total 53184:
  //  GEMM : As  [8 mt][8 c][16 r][8] f16 @0      (16384)
  //         BTs [16 nt][8 c][16 n][8] f16 @16384 (32768)
  //  attn : kvT [128 col][124 row] f16 @16384    (31744, reuses BTs)
  //  post : attO f32 [3][128] @0 | h1s f32 [3][128] @1536 (reuse As)
  //  pers : qs f32 [3][128] @49152 | srcs @50688 | scs f32 [6][40] @52224
  __shared__ __align__(16) char smem[53184];
  half_t* As   = (half_t*)(smem);
  half_t* BTs  = (half_t*)(smem + 16384);
  half_t* kvT  = (half_t*)(smem + 16384);
  float*  attO = (float*)(smem);
  float*  h1s  = (float*)(smem + 1536);
  float*  qs   = (float*)(smem + 49152);
  float*  srcs = (float*)(smem + 50688);
  float*  scs  = (float*)(smem + 52224);

  const int tid = threadIdx.x;
  const int bbase = blockIdx.x * 3;

  // ---- stage src rows (3 x 128 f32) ----
  if (tid < 384) {
    int g = tid >> 7, dd = tid & 127;
    srcs[tid] = nf[(size_t)src_idx[bbase + g] * 128 + dd];
  }
  __syncthreads();

  // ---- q = src @ Wq_top + qbias ----
  if (tid < 384) {
    int g = tid >> 7, jj = tid & 127;
    const float* sg = srcs + g * 128;
    float s = qbias_l[jj];
    #pragma unroll 8
    for (int d = 0; d < 128; ++d) s += sg[d] * Wq_l[d * 128 + jj];
    qs[tid] = s;        // first read is after many barriers
  }

  // ---- per-thread row info for A staging (4 threads per row) ----
  const int r = tid >> 2, p = tid & 3;
  float dval = 0.f;
  const float* gb_ne = nullptr;
  const float* gb_ef = nullptr;
  if (r < 120) {
    int g = r / 40;
    int n = r - g * 40;
    int bg = bbase + g;
    int rowidx = bg * KNN + n;
    dval = tsv[bg / ts_div] - etimes[rowidx];
    gb_ne = ne_direct ? (ne_src + (size_t)rowidx * 128)
                      : (ne_src + (size_t)neigh[rowidx] * 128);
    gb_ef = ef + (size_t)eidx[rowidx] * 128;
  }

  floatx4 acc[4][4];
  #pragma unroll
  for (int mi = 0; mi < 4; ++mi)
    #pragma unroll
    for (int ni = 0; ni < 4; ++ni)
      acc[mi][ni] = (floatx4){0.f, 0.f, 0.f, 0.f};

  const int lane = tid & 63;
  const int wv   = tid >> 6;
  const int wm   = (wv & 1) * 64;     // 0 / 64
  const int wn   = (wv >> 1) * 64;    // 0 / 64 / 128 / 192
  const int l15  = lane & 15;
  const int q4   = lane >> 4;

  // A destination: this thread fills chunks c = 2p, 2p+1 of row r
  half_t* Adst = As + ((((r >> 4) * 8) + 2 * p) * 16 + (r & 15)) * 8;
  // B: thread covers col bn, k-half pb (chunks pb*4 .. pb*4+3)
  const int bn = tid >> 1, pb = tid & 1;
  half_t* Bdst = BTs + ((((bn >> 4) * 8) + pb * 4) * 16 + (bn & 15)) * 8;

  // ---- K-loop: 6 chunks of 64 (seg 0=NF, 1=time, 2=EF) ----
  for (int kc = 0; kc < 6; ++kc) {
    const int seg  = kc >> 1;
    const int soff = (kc & 1) * 64;

    if (r < 120) {
      if (seg == 1) {
        half8 h0, h1;
        #pragma unroll
        for (int u = 0; u < 8; ++u) {
          int c = soff + p * 16 + u;
          h0[u] = (half_t)__cosf(__builtin_fmaf(dval, tw[c], tb[c]));
        }
        #pragma unroll
        for (int u = 0; u < 8; ++u) {
          int c = soff + p * 16 + 8 + u;
          h1[u] = (half_t)__cosf(__builtin_fmaf(dval, tw[c], tb[c]));
        }
        *(half8*)(Adst)       = h0;
        *(half8*)(Adst + 128) = h1;   // next chunk = +16*8 f16
      } else {
        const float* gb = (seg == 0 ? gb_ne : gb_ef) + soff + p * 16;
        float4 v0 = ((const float4*)gb)[0];
        float4 v1 = ((const float4*)gb)[1];
        float4 v2 = ((const float4*)gb)[2];
        float4 v3 = ((const float4*)gb)[3];
        half8 h0, h1;
        h0[0] = (half_t)v0.x; h0[1] = (half_t)v0.y;
        h0[2] = (half_t)v0.z; h0[3] = (half_t)v0.w;
        h0[4] = (half_t)v1.x; h0[5] = (half_t)v1.y;
        h0[6] = (half_t)v1.z; h0[7] = (half_t)v1.w;
        h1[0] = (half_t)v2.x; h1[1] = (half_t)v2.y;
        h1[2] = (half_t)v2.z; h1[3] = (half_t)v2.w;
        h1[4] = (half_t)v3.x; h1[5] = (half_t)v3.y;
        h1[6] = (half_t)v3.z; h1[7] = (half_t)v3.w;
        *(half8*)(Adst)       = h0;
        *(half8*)(Adst + 128) = h1;
      }
    } else {
      half8 z = {};
      *(half8*)(Adst)       = z;
      *(half8*)(Adst + 128) = z;
    }

    // stage BT: 64 B per thread, contiguous from WkvT
    {
      const uint4* gsrc = (const uint4*)(WkvT_l + (size_t)bn * 384 + kc * 64 + pb * 32);
      uint4 w0 = gsrc[0], w1 = gsrc[1], w2 = gsrc[2], w3 = gsrc[3];
      *(uint4*)(Bdst)       = w0;
      *(uint4*)(Bdst + 128) = w1;
      *(uint4*)(Bdst + 256) = w2;
      *(uint4*)(Bdst + 384) = w3;
    }
    __syncthreads();

    #pragma unroll
    for (int ks = 0; ks < 2; ++ks) {
      const int c = ks * 4 + q4;
      half8 a[4];
      #pragma unroll
      for (int mi = 0; mi < 4; ++mi)
        a[mi] = *(half8*)(As + ((((wm >> 4) + mi) * 8 + c) * 16 + l15) * 8);
      #pragma unroll
      for (int ni = 0; ni < 4; ++ni) {
        half8 b = *(half8*)(BTs + ((((wn >> 4) + ni) * 8 + c) * 16 + l15) * 8);
        #pragma unroll
        for (int mi = 0; mi < 4; ++mi)
          acc[mi][ni] = __builtin_amdgcn_mfma_f32_16x16x32_f16(a[mi], b, acc[mi][ni], 0, 0, 0);
      }
    }
    __syncthreads();
  }

  // ---- kk pass: waves with cols 0..127 write kk^T ----
  if (wv < 4) {
    #pragma unroll
    for (int mi = 0; mi < 4; ++mi) {
      int row0 = wm + mi * 16 + q4 * 4;   // C/D: row = quad*4 + reg
      if (row0 < 120) {
        #pragma unroll
        for (int ni = 0; ni < 4; ++ni) {
          int col = wn + ni * 16 + l15;
          half4_t h;
          h[0] = (half_t)acc[mi][ni][0];
          h[1] = (half_t)acc[mi][ni][1];
          h[2] = (half_t)acc[mi][ni][2];
          h[3] = (half_t)acc[mi][ni][3];
          *(half4_t*)(kvT + col * KVPAD + row0) = h;
        }
      }
    }
  }
  __syncthreads();

  // ---- scores: thread per (g,h,n), 240 threads ----
  if (tid < 240) {
    int g = tid / 80;
    int rem = tid - g * 80;
    int h = rem / 40;
    int n = rem - h * 40;
    bool masked = (neigh[(bbase + g) * KNN + n] == 0);
    const float* qrow = qs + g * 128 + h * 64;
    int row = g * 40 + n;
    float s = 0.f;
    #pragma unroll 8
    for (int d = 0; d < 64; ++d)
      s += qrow[d] * (float)kvT[(h * 64 + d) * KVPAD + row];
    scs[tid] = masked ? -1e9f : s * 0.125f;
  }
  __syncthreads();

  // ---- softmax: one wave per (g,h); vv pass concurrently on waves 4..7 ----
  if (wv < 6) {
    float v = (lane < 40) ? scs[wv * 40 + lane] : -1e30f;
    float m = v;
    #pragma unroll
    for (int o = 32; o; o >>= 1) m = fmaxf(m, __shfl_xor(m, o));
    float e = (lane < 40) ? __expf(v - m) : 0.f;
    float ssum = e;
    #pragma unroll
    for (int o = 32; o; o >>= 1) ssum += __shfl_xor(ssum, o);
    if (lane < 40) scs[wv * 40 + lane] = e / ssum;
  }
  if (wv >= 4) {   // cols 128..255 = vv -> overwrite kvT (kk reads done)
    #pragma unroll
    for (int mi = 0; mi < 4; ++mi) {
      int row0 = wm + mi * 16 + q4 * 4;
      if (row0 < 120) {
        #pragma unroll
        for (int ni = 0; ni < 4; ++ni) {
          int col = wn - 128 + ni * 16 + l15;
          half4_t h;
          h[0] = (half_t)acc[mi][ni][0];
          h[1] = (half_t)acc[mi][ni][1];
          h[2] = (half_t)acc[mi][ni][2];
          h[3] = (half_t)acc[mi][ni][3];
          *(half4_t*)(kvT + col * KVPAD + row0) = h;
        }
      }
    }
  }
  __syncthreads();

  // ---- attnOut[g][d] = sum_n attn * vv ----
  if (tid < 384) {
    int g = tid >> 7, dcol = tid & 127, h = dcol >> 6;
    const float* attn = scs + (g * 2 + h) * 40;
    const half_t* vcol = kvT + dcol * KVPAD + g * 40;
    float s = 0.f;
    #pragma unroll 8
    for (int n = 0; n < 40; ++n) s += attn[n] * (float)vcol[n];
    attO[tid] = s;
  }
  __syncthreads();

  // ---- h1 = relu(attnOut @ Wofc1 + src @ fc1_bot)  (h1s region disjoint) ----
  if (tid < 384) {
    int g = tid >> 7, jj = tid & 127;
    const float* ag = attO + g * 128;
    const float* sg = srcs + g * 128;
    float s = 0.f;
    #pragma unroll 8
    for (int d = 0; d < 128; ++d)
      s += ag[d] * Wofc1_l[d * 128 + jj] + sg[d] * fc1b_l[d * 128 + jj];
    h1s[tid] = fmaxf(s, 0.f);
  }
  __syncthreads();

  // ---- emb = h1 @ fc2 -> out ----
  if (tid < 384) {
    int g = tid >> 7, ii = tid & 127;
    const float* hg = h1s + g * 128;
    float s = 0.f;
    #pragma unroll 8
    for (int j = 0; j < 128; ++j) s += hg[j] * fc2_l[j * 128 + ii];
    out[(size_t)(bbase + g) * 128 + ii] = s;
  }
}

// ---------------------------------------------------------------------------
extern "C" void kernel_launch(void* const* d_in, const int* in_sizes, int n_in,
                              void* d_out, int out_size, void* d_ws, size_t ws_size,
                              hipStream_t stream) {
  const float* nf      = (const float*)d_in[0];
  const float* ef      = (const float*)d_in[1];
  const float* tw      = (const float*)d_in[2];
  const float* tb      = (const float*)d_in[3];
  const float* Wq      = (const float*)d_in[4];
  const float* Wk      = (const float*)d_in[5];
  const float* Wv      = (const float*)d_in[6];
  const float* Wo      = (const float*)d_in[7];
  const float* fc1     = (const float*)d_in[8];
  const float* fc2     = (const float*)d_in[9];
  const int*   srcn    = (const int*)d_in[10];
  const float* ts      = (const float*)d_in[11];
  const int*   neigh2  = (const int*)d_in[12];
  const int*   eidx2   = (const int*)d_in[13];
  const float* etimes2 = (const float*)d_in[14];
  const int*   neigh1  = (const int*)d_in[15];
  const int*   eidx1   = (const int*)d_in[16];
  const float* etimes1 = (const float*)d_in[17];

  // workspace layout (16B aligned)
  half_t* WkvT  = (half_t*)d_ws;                          // 393216 B
  float*  qbias = (float*)((char*)d_ws + 393216);         // 1024 B
  float*  Wofc1 = (float*)((char*)d_ws + 394240);         // 131072 B
  float*  emb1  = (float*)((char*)d_ws + 525312);         // 6144000 B

  precompute_kernel<<<dim3(897), dim3(256), 0, stream>>>(
      Wq, Wk, Wv, Wo, fc1, tb, WkvT, qbias, Wofc1);

  // layer 0: 12000 batches, 3 per block
  hop_kernel<<<dim3(4000), dim3(512), 0, stream>>>(
      nf, nf, 0, ef, neigh2, ts, 40, neigh1, eidx1, etimes1, tw, tb,
      Wq, qbias, WkvT, Wofc1, fc1 + 16384, fc2, emb1);

  // layer 1: 300 batches, 3 per block
  hop_kernel<<<dim3(100), dim3(512), 0, stream>>>(
      nf, emb1, 1, ef, srcn, ts, 1, neigh2, eidx2, etimes2, tw, tb,
      Wq + 32768, qbias + 128, WkvT + 98304, Wofc1 + 16384,
      fc1 + 32768 + 16384, fc2 + 16384, (float*)d_out);
}

// Round 3
// 737.031 us; speedup vs baseline: 1.0737x; 1.0703x over previous
//
#include <hip/hip_runtime.h>
#include <cstdint>

typedef _Float16 half_t;
typedef _Float16 half8  __attribute__((ext_vector_type(8)));
typedef _Float16 half4_t __attribute__((ext_vector_type(4)));
typedef _Float16 h2f    __attribute__((ext_vector_type(2)));
typedef float    floatx4 __attribute__((ext_vector_type(4)));

#define KNN 40
#define KVPAD 124

// ---------------- workspace layout (bytes) ----------------
#define WS_NF16    0ull
#define WS_EMB16   25600000ull
#define WS_WKVT    28672000ull
#define WS_WQ4     29065216ull   // 2 layers x 65536 B
#define WS_W1A4    29196288ull
#define WS_W1B4    29327360ull
#define WS_W24     29458432ull
#define WS_QBIAS   29589504ull
#define WS_WOFTMP  29590528ull
#define WS_ZERO    29721600ull
#define WS_EF16    29721856ull
#define WS_TOTAL_FULL (WS_EF16 + 128000000ull)

// global -> LDS direct copy, 16 B per lane, dest = wave-uniform base + lane*16
__device__ __forceinline__ void ld16(const void* g, void* l) {
  __builtin_amdgcn_global_load_lds(
      (const __attribute__((address_space(1))) unsigned int*)(uintptr_t)g,
      (__attribute__((address_space(3))) unsigned int*)(uintptr_t)l, 16, 0, 0);
}

__device__ __forceinline__ float dot4(half4_t a, half4_t b, float s) {
  s = __builtin_amdgcn_fdot2((h2f){a[0], a[1]}, (h2f){b[0], b[1]}, s, false);
  s = __builtin_amdgcn_fdot2((h2f){a[2], a[3]}, (h2f){b[2], b[3]}, s, false);
  return s;
}

// ---------------------------------------------------------------------------
__global__ __launch_bounds__(256) void cvt_kernel(
    const float* __restrict__ src, half_t* __restrict__ dst, int n8) {
  int stride = gridDim.x * 256;
  for (int i = blockIdx.x * 256 + threadIdx.x; i < n8; i += stride) {
    float4 a = *((const float4*)src + 2 * (size_t)i);
    float4 b = *((const float4*)src + 2 * (size_t)i + 1);
    half8 h;
    h[0] = (half_t)a.x; h[1] = (half_t)a.y; h[2] = (half_t)a.z; h[3] = (half_t)a.w;
    h[4] = (half_t)b.x; h[5] = (half_t)b.y; h[6] = (half_t)b.z; h[7] = (half_t)b.w;
    *((half8*)dst + i) = h;
  }
}

// decode t -> (l, d4, j, e) for the 4-row-pack layout: idx = l*16384 + (d4*128+j)*4 + e
#define PK_DECODE(t) int l = (t) >> 14; int u = (t) & 16383; \
  int d4 = u >> 9; int v = u & 511; int j = v >> 2; int e = v & 3;

__global__ __launch_bounds__(256) void precompute_w(
    const float* __restrict__ Wq, const float* __restrict__ Wk,
    const float* __restrict__ Wv, const float* __restrict__ Wo,
    const float* __restrict__ fc1, const float* __restrict__ fc2,
    const float* __restrict__ time_b,
    half_t* __restrict__ WkvT, float* __restrict__ qbias,
    float* __restrict__ woftmp, half_t* __restrict__ Wq4,
    half_t* __restrict__ W1b4, half_t* __restrict__ W24,
    half_t* __restrict__ zrow)
{
  int blk = blockIdx.x, tid = threadIdx.x;
  if (blk < 768) {
    int t = blk * 256 + tid;            // [0, 2*256*384)
    int l = t / 98304;
    int r = t - l * 98304;
    int n = r / 384;
    int k = r - n * 384;
    float vv = (n < 128) ? Wk[l * 49152 + k * 128 + n]
                         : Wv[l * 49152 + k * 128 + (n - 128)];
    WkvT[t] = (half_t)vv;
  } else if (blk == 768) {
    if (tid < 128) zrow[tid] = (half_t)0.f;
    int l = tid >> 7, j = tid & 127;
    float s = 0.f;
    for (int d = 0; d < 128; ++d)
      s += cosf(time_b[d]) * Wq[l * 32768 + (128 + d) * 128 + j];
    qbias[l * 128 + j] = s;
  } else if (blk < 897) {
    int t = (blk - 769) * 256 + tid;    // Wofc1 = Wo @ fc1_top (f32 temp)
    int l = t >> 14;
    int r = t & 16383;
    int dd = r >> 7, j = r & 127;
    float s = 0.f;
    for (int m = 0; m < 128; ++m)
      s += Wo[l * 16384 + dd * 128 + m] * fc1[l * 32768 + m * 128 + j];
    woftmp[t] = s;
  } else if (blk < 1025) {
    int t = (blk - 897) * 256 + tid;
    PK_DECODE(t);
    Wq4[t] = (half_t)Wq[l * 32768 + (4 * d4 + e) * 128 + j];
  } else if (blk < 1153) {
    int t = (blk - 1025) * 256 + tid;
    PK_DECODE(t);
    W1b4[t] = (half_t)fc1[l * 32768 + (128 + 4 * d4 + e) * 128 + j];
  } else {
    int t = (blk - 1153) * 256 + tid;
    PK_DECODE(t);
    W24[t] = (half_t)fc2[l * 16384 + (4 * d4 + e) * 128 + j];
  }
}

__global__ __launch_bounds__(256) void precompute_w2(
    const float* __restrict__ woftmp, half_t* __restrict__ W1a4) {
  int t = blockIdx.x * 256 + threadIdx.x;
  PK_DECODE(t);
  W1a4[t] = (half_t)woftmp[l * 16384 + (4 * d4 + e) * 128 + j];
}

// ---------------------------------------------------------------------------
// Fused hop aggregation. 512 thr = 8 waves, 3 batches/block (120 kv rows).
// A/B staged via global_load_lds in MFMA-fragment order; A double-buffered.
// ---------------------------------------------------------------------------
template <bool EF16, bool L1DIR>
__global__ __launch_bounds__(512, 4) void hop_kernel(
    const float*  __restrict__ nf,
    const half_t* __restrict__ ne16,     // L0: nf16 (gather via neigh); L1: emb116 direct
    const half_t* __restrict__ ef16,
    const float*  __restrict__ ef32,
    const int*    __restrict__ src_idx,
    const float*  __restrict__ tsv,
    const int*    __restrict__ neigh,
    const int*    __restrict__ eidx,
    const float*  __restrict__ etimes,
    const float*  __restrict__ tw,
    const float*  __restrict__ tb,
    const half_t* __restrict__ Wq4_l,
    const float*  __restrict__ qbias_l,
    const half_t* __restrict__ WkvT_l,
    const half_t* __restrict__ W1a4_l,
    const half_t* __restrict__ W1b4_l,
    const half_t* __restrict__ W24_l,
    const half_t* __restrict__ zrow,
    half_t* __restrict__ out16,
    float*  __restrict__ out32)
{
  // LDS: As0 @0 (16K), As1 @16384 (16K), BTs/kvT @32768 (32K), persists @65536
  __shared__ __align__(16) char smem[71360];
  half_t* BTs  = (half_t*)(smem + 32768);
  half_t* kvT  = (half_t*)(smem + 32768);
  float*  tw_s = (float*)(smem + 65536);
  float*  tb_s = (float*)(smem + 66048);
  float*  qs   = (float*)(smem + 66560);
  half_t* s16  = (half_t*)(smem + 68096);
  half_t* aO16 = (half_t*)(smem + 68864);
  half_t* h116 = (half_t*)(smem + 69632);
  float*  scs  = (float*)(smem + 70400);

  const int tid = threadIdx.x;
  const int bbase = blockIdx.x * 3;
  const int lane = tid & 63, wv = tid >> 6;
  const int l15 = lane & 15, q4 = lane >> 4;
  const int wm = (wv & 1) * 64, wn = (wv >> 1) * 64;

  // ---- setup ----
  if (tid < 128) { tw_s[tid] = tw[tid]; tb_s[tid] = tb[tid]; }
  if (tid < 96) {
    int g = tid >> 5, d4 = tid & 31;
    float4 v4 = *(const float4*)(nf + (size_t)src_idx[bbase + g] * 128 + d4 * 4);
    half4_t h;
    h[0] = (half_t)v4.x; h[1] = (half_t)v4.y; h[2] = (half_t)v4.z; h[3] = (half_t)v4.w;
    *(half4_t*)(s16 + g * 128 + d4 * 4) = h;
  }

  // per-lane A-row setup (row r = wv*16 + l15, folded q4*8 column offset)
  const int r = wv * 16 + l15;
  const bool valid = (r < 120);
  float dval = 0.f;
  const half_t* pNE = zrow + q4 * 8;
  const half_t* pEF = zrow + q4 * 8;
  if (valid) {
    int g = r / 40, n = r - g * 40;
    int bg = bbase + g;
    int rowidx = bg * KNN + n;
    dval = tsv[L1DIR ? bg : (bg / 40)] - etimes[rowidx];
    pNE = (L1DIR ? ne16 + (size_t)rowidx * 128
                 : ne16 + (size_t)neigh[rowidx] * 128) + q4 * 8;
    if (EF16) pEF = ef16 + (size_t)eidx[rowidx] * 128 + q4 * 8;
  }
  // fallback EF(f32) per-thread setup (4 threads/row)
  const float* gbe32 = nullptr;
  const int rr = tid >> 2, pp = tid & 3;
  if (!EF16 && rr < 120) {
    int g2 = rr / 40, n2 = rr - g2 * 40;
    gbe32 = ef32 + (size_t)eidx[(bbase + g2) * KNN + n2] * 128 + pp * 16;
  }

  // B per-lane source base (f16 elems)
  const half_t* bBase = WkvT_l + (size_t)(2 * wv * 16 + l15) * 384 + q4 * 8;

  floatx4 acc[4][4];
  #pragma unroll
  for (int mi = 0; mi < 4; ++mi)
    #pragma unroll
    for (int ni = 0; ni < 4; ++ni) acc[mi][ni] = (floatx4){0.f, 0.f, 0.f, 0.f};

  auto issueA = [&](const half_t* p, int koff, char* buf) {
    ld16(p + koff,      buf + wv * 2048);
    ld16(p + koff + 32, buf + wv * 2048 + 1024);
  };
  auto issueB = [&](int kc) {
    const half_t* bp = bBase + kc * 64;
    ld16(bp,          (char*)BTs + wv * 4096);
    ld16(bp + 32,     (char*)BTs + wv * 4096 + 1024);
    ld16(bp + 6144,   (char*)BTs + wv * 4096 + 2048);
    ld16(bp + 6176,   (char*)BTs + wv * 4096 + 3072);
  };
  auto cosA = [&](int koff, char* buf) {
    #pragma unroll
    for (int i = 0; i < 2; ++i) {
      int c = i * 4 + q4;
      half8 h;
      #pragma unroll
      for (int j = 0; j < 8; ++j) {
        float ang = __builtin_fmaf(dval, tw_s[koff + c * 8 + j], tb_s[koff + c * 8 + j]);
        h[j] = valid ? (half_t)__cosf(ang) : (half_t)0.f;
      }
      *(half8*)(buf + wv * 2048 + i * 1024 + lane * 16) = h;
    }
  };
  auto efA32 = [&](int koff, char* buf) {
    half8 h0 = {}, h1 = {};
    if (rr < 120) {
      const float* gb = gbe32 + koff;
      float4 v0 = ((const float4*)gb)[0];
      float4 v1 = ((const float4*)gb)[1];
      float4 v2 = ((const float4*)gb)[2];
      float4 v3 = ((const float4*)gb)[3];
      h0[0] = (half_t)v0.x; h0[1] = (half_t)v0.y; h0[2] = (half_t)v0.z; h0[3] = (half_t)v0.w;
      h0[4] = (half_t)v1.x; h0[5] = (half_t)v1.y; h0[6] = (half_t)v1.z; h0[7] = (half_t)v1.w;
      h1[0] = (half_t)v2.x; h1[1] = (half_t)v2.y; h1[2] = (half_t)v2.z; h1[3] = (half_t)v2.w;
      h1[4] = (half_t)v3.x; h1[5] = (half_t)v3.y; h1[6] = (half_t)v3.z; h1[7] = (half_t)v3.w;
    }
    half_t* Ad = (half_t*)buf + (((rr >> 4) * 8) + 2 * pp) * 128 + (rr & 15) * 8;
    *(half8*)Ad = h0;
    *(half8*)(Ad + 128) = h1;
  };
  auto mfma_step = [&](const char* abuf) {
    #pragma unroll
    for (int ks = 0; ks < 2; ++ks) {
      int c = ks * 4 + q4;
      half8 a[4];
      #pragma unroll
      for (int mi = 0; mi < 4; ++mi)
        a[mi] = *(const half8*)((const half_t*)abuf + (((wm >> 4) + mi) * 8 + c) * 128 + l15 * 8);
      #pragma unroll
      for (int ni = 0; ni < 4; ++ni) {
        half8 bfr = *(const half8*)(BTs + (((wn >> 4) + ni) * 8 + c) * 128 + l15 * 8);
        #pragma unroll
        for (int mi = 0; mi < 4; ++mi)
          acc[mi][ni] = __builtin_amdgcn_mfma_f32_16x16x32_f16(a[mi], bfr, acc[mi][ni], 0, 0, 0);
      }
    }
  };

  // ---- prologue: A(0)->As0, A(1)->As1, Wq4 -> BTs ----
  issueA(pNE, 0, smem);
  issueA(pNE, 64, smem + 16384);
  {
    const char* sw = (const char*)Wq4_l + wv * 4096 + lane * 16;
    char* dw = (char*)BTs + wv * 4096;
    ld16(sw, dw); ld16(sw + 1024, dw + 1024);
    ld16(sw + 2048, dw + 2048); ld16(sw + 3072, dw + 3072);
  }
  __syncthreads();

  // ---- q = src @ Wq_top + qbias (from LDS f16) ----
  if (tid < 384) {
    int gq = tid >> 7, jj = tid & 127;
    float s = qbias_l[jj];
    #pragma unroll 8
    for (int d4 = 0; d4 < 32; ++d4) {
      half4_t w = *(const half4_t*)(BTs + (d4 * 128 + jj) * 4);
      half4_t a = *(const half4_t*)(s16 + gq * 128 + d4 * 4);
      s = dot4(w, a, s);
    }
    qs[gq * 128 + jj] = s;
  }
  __syncthreads();          // BTs free

  // ---- K-loop (software-pipelined A, single-buffer B) ----
  issueB(0); __syncthreads(); mfma_step(smem);          __syncthreads();
  cosA(0, smem);                                         // A(2) -> As0
  issueB(1); __syncthreads(); mfma_step(smem + 16384);  __syncthreads();
  cosA(64, smem + 16384);                                // A(3) -> As1
  issueB(2); __syncthreads(); mfma_step(smem);          __syncthreads();
  if (EF16) issueA(pEF, 0, smem); else efA32(0, smem);   // A(4) -> As0
  issueB(3); __syncthreads(); mfma_step(smem + 16384);  __syncthreads();
  if (EF16) issueA(pEF, 64, smem + 16384); else efA32(64, smem + 16384); // A(5)
  issueB(4); __syncthreads(); mfma_step(smem);          __syncthreads();
  issueB(5); __syncthreads(); mfma_step(smem + 16384);  __syncthreads();

  // ---- stage W1a4 -> As region (overlaps attention phases) ----
  {
    const char* sw = (const char*)W1a4_l + wv * 4096 + lane * 16;
    char* dw = smem + wv * 4096;
    ld16(sw, dw); ld16(sw + 1024, dw + 1024);
    ld16(sw + 2048, dw + 2048); ld16(sw + 3072, dw + 3072);
  }

  // ---- kk -> kvT (cols 0..127) ----
  if (wv < 4) {
    #pragma unroll
    for (int mi = 0; mi < 4; ++mi) {
      int row0 = wm + mi * 16 + q4 * 4;
      if (row0 < 120) {
        #pragma unroll
        for (int ni = 0; ni < 4; ++ni) {
          int col = wn + ni * 16 + l15;
          half4_t h;
          h[0] = (half_t)acc[mi][ni][0]; h[1] = (half_t)acc[mi][ni][1];
          h[2] = (half_t)acc[mi][ni][2]; h[3] = (half_t)acc[mi][ni][3];
          *(half4_t*)(kvT + col * KVPAD + row0) = h;
        }
      }
    }
  }
  __syncthreads();

  // ---- scores ----
  if (tid < 240) {
    int g = tid / 80;
    int rem = tid - g * 80;
    int h = rem / 40;
    int n = rem - h * 40;
    bool masked = (neigh[(bbase + g) * KNN + n] == 0);
    const float* qrow = qs + g * 128 + h * 64;
    int row = g * 40 + n;
    float s = 0.f;
    #pragma unroll 8
    for (int d = 0; d < 64; ++d)
      s += qrow[d] * (float)kvT[(h * 64 + d) * KVPAD + row];
    scs[tid] = masked ? -1e9f : s * 0.125f;
  }
  __syncthreads();

  // ---- softmax (waves 0..5) + vv -> kvT (waves 4..7) ----
  if (wv < 6) {
    float v = (lane < 40) ? scs[wv * 40 + lane] : -1e30f;
    float m = v;
    #pragma unroll
    for (int o = 32; o; o >>= 1) m = fmaxf(m, __shfl_xor(m, o));
    float e = (lane < 40) ? __expf(v - m) : 0.f;
    float ssum = e;
    #pragma unroll
    for (int o = 32; o; o >>= 1) ssum += __shfl_xor(ssum, o);
    if (lane < 40) scs[wv * 40 + lane] = e / ssum;
  }
  if (wv >= 4) {
    #pragma unroll
    for (int mi = 0; mi < 4; ++mi) {
      int row0 = wm + mi * 16 + q4 * 4;
      if (row0 < 120) {
        #pragma unroll
        for (int ni = 0; ni < 4; ++ni) {
          int col = wn - 128 + ni * 16 + l15;
          half4_t h;
          h[0] = (half_t)acc[mi][ni][0]; h[1] = (half_t)acc[mi][ni][1];
          h[2] = (half_t)acc[mi][ni][2]; h[3] = (half_t)acc[mi][ni][3];
          *(half4_t*)(kvT + col * KVPAD + row0) = h;
        }
      }
    }
  }
  __syncthreads();

  // ---- attnOut -> aO16 ----
  if (tid < 384) {
    int g = tid >> 7, dcol = tid & 127, h = dcol >> 6;
    const float* attn = scs + (g * 2 + h) * 40;
    const half_t* vcol = kvT + dcol * KVPAD + g * 40;
    float s = 0.f;
    #pragma unroll 8
    for (int n = 0; n < 40; ++n) s += attn[n] * (float)vcol[n];
    aO16[g * 128 + dcol] = (half_t)s;
  }
  __syncthreads();          // aO16 visible; kvT dead; W1a4 landed

  // ---- stage W1b4 -> BTs; h1 pass1 from As(W1a4) ----
  {
    const char* sw = (const char*)W1b4_l + wv * 4096 + lane * 16;
    char* dw = (char*)BTs + wv * 4096;
    ld16(sw, dw); ld16(sw + 1024, dw + 1024);
    ld16(sw + 2048, dw + 2048); ld16(sw + 3072, dw + 3072);
  }
  float p1 = 0.f;
  if (tid < 384) {
    int g = tid >> 7, jj = tid & 127;
    #pragma unroll 8
    for (int d4 = 0; d4 < 32; ++d4) {
      half4_t w = *(const half4_t*)((const half_t*)smem + (d4 * 128 + jj) * 4);
      half4_t a = *(const half4_t*)(aO16 + g * 128 + d4 * 4);
      p1 = dot4(w, a, p1);
    }
  }
  __syncthreads();          // W1b4 landed; As free

  // ---- stage W24 -> As; h1 pass2 + relu ----
  {
    const char* sw = (const char*)W24_l + wv * 4096 + lane * 16;
    char* dw = smem + wv * 4096;
    ld16(sw, dw); ld16(sw + 1024, dw + 1024);
    ld16(sw + 2048, dw + 2048); ld16(sw + 3072, dw + 3072);
  }
  if (tid < 384) {
    int g = tid >> 7, jj = tid & 127;
    float p2 = p1;
    #pragma unroll 8
    for (int d4 = 0; d4 < 32; ++d4) {
      half4_t w = *(const half4_t*)(BTs + (d4 * 128 + jj) * 4);
      half4_t a = *(const half4_t*)(s16 + g * 128 + d4 * 4);
      p2 = dot4(w, a, p2);
    }
    h116[g * 128 + jj] = (half_t)fmaxf(p2, 0.f);
  }
  __syncthreads();          // W24 landed; h116 visible

  // ---- fc2 -> out ----
  if (tid < 384) {
    int g = tid >> 7, ii = tid & 127;
    float s = 0.f;
    #pragma unroll 8
    for (int j4 = 0; j4 < 32; ++j4) {
      half4_t w = *(const half4_t*)((const half_t*)smem + (j4 * 128 + ii) * 4);
      half4_t a = *(const half4_t*)(h116 + g * 128 + j4 * 4);
      s = dot4(w, a, s);
    }
    if (L1DIR) out32[(size_t)(bbase + g) * 128 + ii] = s;
    else       out16[(size_t)(bbase + g) * 128 + ii] = (half_t)s;
  }
}

// ---------------------------------------------------------------------------
extern "C" void kernel_launch(void* const* d_in, const int* in_sizes, int n_in,
                              void* d_out, int out_size, void* d_ws, size_t ws_size,
                              hipStream_t stream) {
  const float* nf      = (const float*)d_in[0];
  const float* ef      = (const float*)d_in[1];
  const float* tw      = (const float*)d_in[2];
  const float* tb      = (const float*)d_in[3];
  const float* Wq      = (const float*)d_in[4];
  const float* Wk      = (const float*)d_in[5];
  const float* Wv      = (const float*)d_in[6];
  const float* Wo      = (const float*)d_in[7];
  const float* fc1     = (const float*)d_in[8];
  const float* fc2     = (const float*)d_in[9];
  const int*   srcn    = (const int*)d_in[10];
  const float* ts      = (const float*)d_in[11];
  const int*   neigh2  = (const int*)d_in[12];
  const int*   eidx2   = (const int*)d_in[13];
  const float* etimes2 = (const float*)d_in[14];
  const int*   neigh1  = (const int*)d_in[15];
  const int*   eidx1   = (const int*)d_in[16];
  const float* etimes1 = (const float*)d_in[17];

  char* ws = (char*)d_ws;
  half_t* nf16   = (half_t*)(ws + WS_NF16);
  half_t* emb116 = (half_t*)(ws + WS_EMB16);
  half_t* WkvT16 = (half_t*)(ws + WS_WKVT);
  half_t* Wq4    = (half_t*)(ws + WS_WQ4);
  half_t* W1a4   = (half_t*)(ws + WS_W1A4);
  half_t* W1b4   = (half_t*)(ws + WS_W1B4);
  half_t* W24    = (half_t*)(ws + WS_W24);
  float*  qbias  = (float*)(ws + WS_QBIAS);
  float*  woftmp = (float*)(ws + WS_WOFTMP);
  half_t* zrow   = (half_t*)(ws + WS_ZERO);
  half_t* ef16   = (half_t*)(ws + WS_EF16);

  bool full = (ws_size >= WS_TOTAL_FULL);

  cvt_kernel<<<dim3(2048), dim3(256), 0, stream>>>(nf, nf16, 1600000);
  if (full)
    cvt_kernel<<<dim3(4096), dim3(256), 0, stream>>>(ef, ef16, 8000000);
  precompute_w<<<dim3(1281), dim3(256), 0, stream>>>(
      Wq, Wk, Wv, Wo, fc1, fc2, tb, WkvT16, qbias, woftmp, Wq4, W1b4, W24, zrow);
  precompute_w2<<<dim3(128), dim3(256), 0, stream>>>(woftmp, W1a4);

  if (full) {
    hop_kernel<true, false><<<dim3(4000), dim3(512), 0, stream>>>(
        nf, nf16, ef16, ef, neigh2, ts, neigh1, eidx1, etimes1, tw, tb,
        Wq4, qbias, WkvT16, W1a4, W1b4, W24, zrow, emb116, nullptr);
    hop_kernel<true, true><<<dim3(100), dim3(512), 0, stream>>>(
        nf, emb116, ef16, ef, srcn, ts, neigh2, eidx2, etimes2, tw, tb,
        Wq4 + 16384, qbias + 128, WkvT16 + 98304, W1a4 + 16384, W1b4 + 16384,
        W24 + 16384, zrow, emb116, (float*)d_out);
  } else {
    hop_kernel<false, false><<<dim3(4000), dim3(512), 0, stream>>>(
        nf, nf16, ef16, ef, neigh2, ts, neigh1, eidx1, etimes1, tw, tb,
        Wq4, qbias, WkvT16, W1a4, W1b4, W24, zrow, emb116, nullptr);
    hop_kernel<false, true><<<dim3(100), dim3(512), 0, stream>>>(
        nf, emb116, ef16, ef, srcn, ts, neigh2, eidx2, etimes2, tw, tb,
        Wq4 + 16384, qbias + 128, WkvT16 + 98304, W1a4 + 16384, W1b4 + 16384,
        W24 + 16384, zrow, emb116, (float*)d_out);
  }
}